// Round 2
// baseline (1196.731 us; speedup 1.0000x reference)
//
#include <hip/hip_runtime.h>
#include <math.h>

#define L 10
#define B 4
#define H 256
#define W 256
#define HID 100
#define SIGMA 4.0f
#define KSIZE 25
#define KHALF 12
#define MU 0.02f
#define SLOPE 0.01f
#define HW (H*W)

// ---------------------------------------------------------------- helpers

__device__ __forceinline__ float tap2(const float* __restrict__ im, int y, int x) {
    return (x >= 0 && x < W && y >= 0 && y < H) ? im[y * W + x] : 0.f;
}

// bilinear, zeros padding, pixel coords
__device__ __forceinline__ float bilin(const float* __restrict__ im, float x, float y) {
    float xf = floorf(x), yf = floorf(y);
    int x0 = (int)xf, y0 = (int)yf;
    float wx = x - xf, wy = y - yf;
    float v00 = tap2(im, y0, x0),     v01 = tap2(im, y0, x0 + 1);
    float v10 = tap2(im, y0 + 1, x0), v11 = tap2(im, y0 + 1, x0 + 1);
    return v00 * (1.f - wx) * (1.f - wy) + v01 * wx * (1.f - wy)
         + v10 * (1.f - wx) * wy         + v11 * wx * wy;
}

__device__ __forceinline__ void gaussw(float g[KSIZE]) {
    float s = 0.f;
#pragma unroll
    for (int k = 0; k < KSIZE; ++k) {
        float r = ((float)k - (float)KHALF) * (1.f / SIGMA);
        float v = expf(-0.5f * r * r);
        g[k] = v; s += v;
    }
    float inv = 1.f / s;
#pragma unroll
    for (int k = 0; k < KSIZE; ++k) g[k] *= inv;
}

// ---------------------------------------------------------------- init

__global__ void init_kernel(const float* __restrict__ source, const float* __restrict__ z0,
                            float* __restrict__ res0_out, float* __restrict__ rd0,
                            float* __restrict__ phi0, float* __restrict__ image_buf) {
    int idx = blockIdx.x * 256 + threadIdx.x;
    if (idx >= B * HW) return;
    int b = idx / HW, p = idx % HW;
    int y = p / W, x = p % W;
    float z = z0[p];
    res0_out[idx] = z;                        // residuals[0] (B,1,H,W)
    rd0[(size_t)(b * 11 + 0) * HW + p] = z;   // rd channel 0
    image_buf[idx] = source[idx];
    phi0[(size_t)(b * 2 + 0) * HW + p] = (float)x;
    phi0[(size_t)(b * 2 + 1) * HW + p] = (float)y;
}

// ------------------------------------------------- A: sobel + t = -res*g2

__global__ void sobel_kernel(const float* __restrict__ img, const float* __restrict__ res,
                             float* __restrict__ grads_l, float* __restrict__ t) {
    int idx = blockIdx.x * 256 + threadIdx.x;
    if (idx >= B * HW) return;
    int b = idx / HW, p = idx % HW;
    int y = p / W, x = p % W;
    const float* im = img + (size_t)b * HW;
    int ym = max(y - 1, 0), yp = min(y + 1, H - 1);
    int xm = max(x - 1, 0), xp = min(x + 1, W - 1);
    float a00 = im[ym * W + xm], a01 = im[ym * W + x], a02 = im[ym * W + xp];
    float a10 = im[y  * W + xm],                        a12 = im[y  * W + xp];
    float a20 = im[yp * W + xm], a21 = im[yp * W + x], a22 = im[yp * W + xp];
    float dx = (a02 - a00 + 2.f * (a12 - a10) + a22 - a20) * 0.125f;
    float dy = (a20 - a00 + 2.f * (a21 - a01) + a22 - a02) * 0.125f;
    grads_l[(size_t)(b * 2 + 0) * HW + p] = dx;
    grads_l[(size_t)(b * 2 + 1) * HW + p] = dy;
    float r = res[idx];
    t[(size_t)(b * 2 + 0) * HW + p] = -r * dx;
    t[(size_t)(b * 2 + 1) * HW + p] = -r * dy;
}

// ------------------------------------------------- B/C: separable blur

__global__ void blurv_kernel(const float* __restrict__ t, float* __restrict__ o) {
    int idx = blockIdx.x * 256 + threadIdx.x;
    if (idx >= 2 * B * HW) return;
    int bc = idx / HW, p = idx % HW;
    int y = p / W, x = p % W;
    float g[KSIZE]; gaussw(g);
    const float* base = t + (size_t)bc * HW;
    float acc = 0.f;
#pragma unroll
    for (int k = 0; k < KSIZE; ++k) {
        int yy = y + k - KHALF;
        if (yy >= 0 && yy < H) acc += g[k] * base[yy * W + x];
    }
    o[idx] = acc;
}

__global__ void blurh_kernel(const float* __restrict__ tmp, float* __restrict__ field_l) {
    int idx = blockIdx.x * 256 + threadIdx.x;
    if (idx >= 2 * B * HW) return;
    int bc = idx / HW, p = idx % HW;
    int y = p / W, x = p % W;
    int b = bc >> 1, c = bc & 1;
    float g[KSIZE]; gaussw(g);
    const float* base = tmp + (size_t)bc * HW;
    float acc = 0.f;
#pragma unroll
    for (int k = 0; k < KSIZE; ++k) {
        int xx = x + k - KHALF;
        if (xx >= 0 && xx < W) acc += g[k] * base[y * W + xx];
    }
    field_l[((size_t)(b * H + y) * W + x) * 2 + c] = acc;  // (B,H,W,2)
}

// ------------------------------------------------- D: fused res_block

#define NC 10   // hid channels per chunk

__global__ __launch_bounds__(256)
void resblock_kernel(const float* __restrict__ res_i, const float* __restrict__ img,
                     const float* __restrict__ w1, const float* __restrict__ b1,
                     const float* __restrict__ w2, float* __restrict__ res_out) {
    __shared__ float s_in[2][20][21];     // input tile + halo2, zero-padded
    __shared__ float s_w1[HID * 18];
    __shared__ float s_b1[HID];
    __shared__ float s_w2[HID * 9];
    __shared__ float s_hid[NC][18][19];   // conv1 out over 18x18 (halo1)

    const int tid = threadIdx.y * 16 + threadIdx.x;
    const int b = blockIdx.z;
    const int TY0 = blockIdx.y * 16, TX0 = blockIdx.x * 16;

    for (int q = tid; q < HID * 18; q += 256) s_w1[q] = w1[q];
    for (int q = tid; q < HID * 9;  q += 256) s_w2[q] = w2[q];
    for (int q = tid; q < HID;      q += 256) s_b1[q] = b1[q];

    for (int q = tid; q < 20 * 20; q += 256) {
        int ry = q / 20, rx = q % 20;
        int gy = TY0 - 2 + ry, gx = TX0 - 2 + rx;
        bool v = (gy >= 0 && gy < H && gx >= 0 && gx < W);
        size_t gp = (size_t)b * HW + gy * W + gx;
        s_in[0][ry][rx] = v ? res_i[gp] : 0.f;
        s_in[1][ry][rx] = v ? img[gp]   : 0.f;
    }
    __syncthreads();

    const int ly = threadIdx.y, lx = threadIdx.x;
    float acc = 0.f;

    for (int cc = 0; cc < HID / NC; ++cc) {
        for (int q = tid; q < 18 * 18; q += 256) {
            int ry = q / 18, rx = q % 18;
            // hidden position in global coords; conv2's SAME padding means
            // hidden OUTSIDE the image is ZERO (conv1 output doesn't exist
            // there) — must not compute conv1 on padded input in the halo.
            int gy = TY0 - 1 + ry, gx = TX0 - 1 + rx;
            bool inimg = (gy >= 0 && gy < H && gx >= 0 && gx < W);
            float xv[18];
#pragma unroll
            for (int ic = 0; ic < 2; ++ic)
#pragma unroll
                for (int j = 0; j < 3; ++j)
#pragma unroll
                    for (int i = 0; i < 3; ++i)
                        xv[ic * 9 + j * 3 + i] = s_in[ic][ry + j][rx + i];
#pragma unroll
            for (int c = 0; c < NC; ++c) {
                const float* wp = &s_w1[(cc * NC + c) * 18];
                float h = s_b1[cc * NC + c];
#pragma unroll
                for (int k = 0; k < 18; ++k) h = fmaf(wp[k], xv[k], h);
                h = (h >= 0.f) ? h : SLOPE * h;
                s_hid[c][ry][rx] = inimg ? h : 0.f;
            }
        }
        __syncthreads();
#pragma unroll
        for (int c = 0; c < NC; ++c) {
            const float* wp = &s_w2[(cc * NC + c) * 9];
#pragma unroll
            for (int j = 0; j < 3; ++j)
#pragma unroll
                for (int i = 0; i < 3; ++i)
                    acc = fmaf(wp[j * 3 + i], s_hid[c][ly + j][lx + i], acc);
        }
        __syncthreads();
    }

    size_t gp = (size_t)b * HW + (TY0 + ly) * W + (TX0 + lx);
    res_out[gp] = res_i[gp] + acc * (1.f / (float)L);
}

// ------------------------------------------------- E+F+G: warp rd, warp phi,
// resample source/seg, image update

__global__ void efg_kernel(const float* __restrict__ field,     // (B,H,W,2)
                           const float* __restrict__ res_new,   // residuals[i+1]
                           const float* __restrict__ rd_old, float* __restrict__ rd_new,
                           int nc_old,                          // channels in rd_old = i+1
                           const float* __restrict__ phi_old, float* __restrict__ phi_new,
                           const float* __restrict__ seg, const float* __restrict__ source,
                           float* __restrict__ image_buf, float* __restrict__ image_out) {
    int idx = blockIdx.x * 256 + threadIdx.x;
    if (idx >= B * HW) return;
    int b = idx / HW, p = idx % HW;
    int y = p / W, x = p % W;

    float fx = field[((size_t)(b * HW + p)) * 2 + 0];
    float fy = field[((size_t)(b * HW + p)) * 2 + 1];
    float sx = (float)x - fx * (1.f / (float)L);
    float sy = (float)y - fy * (1.f / (float)L);

    float xf = floorf(sx), yf = floorf(sy);
    int x0 = (int)xf, y0 = (int)yf;
    float wx = sx - xf, wy = sy - yf;
    // fold per-tap validity (zeros padding) into the weights
    float mx0 = (x0 >= 0 && x0 < W) ? 1.f : 0.f;
    float mx1 = (x0 + 1 >= 0 && x0 + 1 < W) ? 1.f : 0.f;
    float my0 = (y0 >= 0 && y0 < H) ? 1.f : 0.f;
    float my1 = (y0 + 1 >= 0 && y0 + 1 < H) ? 1.f : 0.f;
    float W00 = (1.f - wx) * (1.f - wy) * mx0 * my0;
    float W01 = wx * (1.f - wy) * mx1 * my0;
    float W10 = (1.f - wx) * wy * mx0 * my1;
    float W11 = wx * wy * mx1 * my1;
    int xc0 = min(max(x0, 0), W - 1), xc1 = min(max(x0 + 1, 0), W - 1);
    int yc0 = min(max(y0, 0), H - 1), yc1 = min(max(y0 + 1, 0), H - 1);
    int o00 = yc0 * W + xc0, o01 = yc0 * W + xc1;
    int o10 = yc1 * W + xc0, o11 = yc1 * W + xc1;

    float s = 0.f;
    for (int c = 0; c < nc_old; ++c) {
        const float* im = rd_old + (size_t)(b * 11 + c) * HW;
        float v = W00 * im[o00] + W01 * im[o01] + W10 * im[o10] + W11 * im[o11];
        rd_new[(size_t)(b * 11 + c) * HW + p] = v;
        if (c > 0) s += v;
    }
    float rn = res_new[idx];
    rd_new[(size_t)(b * 11 + nc_old) * HW + p] = rn;
    s += rn;

    const float* phx = phi_old + (size_t)(b * 2 + 0) * HW;
    const float* phy = phi_old + (size_t)(b * 2 + 1) * HW;
    float pxn = W00 * phx[o00] + W01 * phx[o01] + W10 * phx[o10] + W11 * phx[o11];
    float pyn = W00 * phy[o00] + W01 * phy[o01] + W10 * phy[o10] + W11 * phy[o11];
    phi_new[(size_t)(b * 2 + 0) * HW + p] = pxn;
    phi_new[(size_t)(b * 2 + 1) * HW + p] = pyn;

    float mask = bilin(seg + (size_t)b * HW, pxn, pyn);
    float sw   = bilin(source + (size_t)b * HW, pxn, pyn);
    float img = sw + s * (MU * MU / (float)L) * mask;
    image_buf[idx] = img;
    image_out[idx] = img;
}

// ---------------------------------------------------------------- launch

extern "C" void kernel_launch(void* const* d_in, const int* in_sizes, int n_in,
                              void* d_out, int out_size, void* d_ws, size_t ws_size,
                              hipStream_t stream) {
    const float* source = (const float*)d_in[0];
    const float* seg    = (const float*)d_in[1];
    const float* z0     = (const float*)d_in[2];
    const float* w1     = (const float*)d_in[3];
    const float* b1     = (const float*)d_in[4];
    const float* w2     = (const float*)d_in[5];
    float* out = (float*)d_out;

    const size_t nPix = (size_t)B * HW;
    float* out_image  = out;                                   // B*HW
    float* out_fields = out + nPix;                            // L*B*HW*2
    float* out_res    = out_fields + (size_t)L * nPix * 2;     // (L+1)*B*HW
    float* out_grads  = out_res + (size_t)(L + 1) * nPix;      // L*B*2*HW

    float* ws        = (float*)d_ws;
    float* t_buf     = ws;                       // 2*B*HW
    float* tmp_buf   = t_buf + 2 * nPix;         // 2*B*HW
    float* image_buf = tmp_buf + 2 * nPix;       // B*HW
    float* phi_buf0  = image_buf + nPix;         // 2*B*HW
    float* phi_buf1  = phi_buf0 + 2 * nPix;      // 2*B*HW
    float* rd_buf0   = phi_buf1 + 2 * nPix;      // 11*B*HW
    float* rd_buf1   = rd_buf0 + 11 * nPix;      // 11*B*HW
    float* phi_buf[2] = { phi_buf0, phi_buf1 };
    float* rd_buf[2]  = { rd_buf0, rd_buf1 };

    dim3 blk(256);
    int gPix = (int)((nPix + 255) / 256);
    int gPix2 = (int)((2 * nPix + 255) / 256);

    init_kernel<<<gPix, blk, 0, stream>>>(source, z0, out_res, rd_buf[0], phi_buf[0], image_buf);

    int cur = 0;
    for (int i = 0; i < L; ++i) {
        sobel_kernel<<<gPix, blk, 0, stream>>>(image_buf, out_res + (size_t)i * nPix,
                                               out_grads + (size_t)i * 2 * nPix, t_buf);
        blurv_kernel<<<gPix2, blk, 0, stream>>>(t_buf, tmp_buf);
        blurh_kernel<<<gPix2, blk, 0, stream>>>(tmp_buf, out_fields + (size_t)i * 2 * nPix);
        dim3 gD(W / 16, H / 16, B), bD(16, 16);
        resblock_kernel<<<gD, bD, 0, stream>>>(out_res + (size_t)i * nPix, image_buf,
                                               w1 + (size_t)i * HID * 18,
                                               b1 + (size_t)i * HID,
                                               w2 + (size_t)i * HID * 9,
                                               out_res + (size_t)(i + 1) * nPix);
        efg_kernel<<<gPix, blk, 0, stream>>>(out_fields + (size_t)i * 2 * nPix,
                                             out_res + (size_t)(i + 1) * nPix,
                                             rd_buf[cur], rd_buf[cur ^ 1], i + 1,
                                             phi_buf[cur], phi_buf[cur ^ 1],
                                             seg, source, image_buf, out_image);
        cur ^= 1;
    }
}

// Round 3
// 903.785 us; speedup vs baseline: 1.3241x; 1.3241x over previous
//
#include <hip/hip_runtime.h>
#include <math.h>

#define L 10
#define B 4
#define H 256
#define W 256
#define HID 100
#define SIGMA 4.0f
#define KSIZE 25
#define KHALF 12
#define MU 0.02f
#define SLOPE 0.01f
#define HW (H*W)

// ---------------------------------------------------------------- helpers

__device__ __forceinline__ float tap2(const float* __restrict__ im, int y, int x) {
    return (x >= 0 && x < W && y >= 0 && y < H) ? im[y * W + x] : 0.f;
}

__device__ __forceinline__ float bilin(const float* __restrict__ im, float x, float y) {
    float xf = floorf(x), yf = floorf(y);
    int x0 = (int)xf, y0 = (int)yf;
    float wx = x - xf, wy = y - yf;
    float v00 = tap2(im, y0, x0),     v01 = tap2(im, y0, x0 + 1);
    float v10 = tap2(im, y0 + 1, x0), v11 = tap2(im, y0 + 1, x0 + 1);
    return v00 * (1.f - wx) * (1.f - wy) + v01 * wx * (1.f - wy)
         + v10 * (1.f - wx) * wy         + v11 * wx * wy;
}

__device__ __forceinline__ void gaussw(float g[KSIZE]) {
    float s = 0.f;
#pragma unroll
    for (int k = 0; k < KSIZE; ++k) {
        float r = ((float)k - (float)KHALF) * (1.f / SIGMA);
        float v = expf(-0.5f * r * r);
        g[k] = v; s += v;
    }
    float inv = 1.f / s;
#pragma unroll
    for (int k = 0; k < KSIZE; ++k) g[k] *= inv;
}

// ---------------------------------------------------------------- init

__global__ void init_kernel(const float* __restrict__ source, const float* __restrict__ z0,
                            float* __restrict__ res0_out, float* __restrict__ rd0,
                            float* __restrict__ phi0, float* __restrict__ image_buf) {
    int idx = blockIdx.x * 256 + threadIdx.x;
    if (idx >= B * HW) return;
    int b = idx / HW, p = idx % HW;
    int y = p / W, x = p % W;
    float z = z0[p];
    res0_out[idx] = z;
    rd0[(size_t)(b * 11 + 0) * HW + p] = z;
    image_buf[idx] = source[idx];
    phi0[(size_t)(b * 2 + 0) * HW + p] = (float)x;
    phi0[(size_t)(b * 2 + 1) * HW + p] = (float)y;
}

// ------------------------------------- fused sobel + t + vblur + hblur
// tile 32x32 of field output per block, 256 threads.

__global__ __launch_bounds__(256)
void field_kernel(const float* __restrict__ img, const float* __restrict__ res,
                  float* __restrict__ grads_l, float* __restrict__ field_l) {
    __shared__ float s_img[58][59];
    __shared__ float s_t[2][56][57];
    __shared__ float s_vb[2][32][57];

    const int tid = threadIdx.x;
    const int b = blockIdx.z;
    const int TY0 = blockIdx.y * 32, TX0 = blockIdx.x * 32;
    const float* imb = img + (size_t)b * HW;
    const float* reb = res + (size_t)b * HW;

    // stage image (58x58), replicate-clamped to the global image border
    for (int q = tid; q < 58 * 58; q += 256) {
        int sy = q / 58, sx = q % 58;
        int gy = min(max(TY0 - 13 + sy, 0), H - 1);
        int gx = min(max(TX0 - 13 + sx, 0), W - 1);
        s_img[sy][sx] = imb[gy * W + gx];
    }
    __syncthreads();

    // sobel + t = -res*g2 over 56x56 (zero outside image: blur zero-pads)
    for (int q = tid; q < 56 * 56; q += 256) {
        int py = q / 56, px = q % 56;
        int sy = py + 1, sx = px + 1;
        float a00 = s_img[sy-1][sx-1], a01 = s_img[sy-1][sx], a02 = s_img[sy-1][sx+1];
        float a10 = s_img[sy  ][sx-1],                         a12 = s_img[sy  ][sx+1];
        float a20 = s_img[sy+1][sx-1], a21 = s_img[sy+1][sx], a22 = s_img[sy+1][sx+1];
        float dx = (a02 - a00 + 2.f * (a12 - a10) + a22 - a20) * 0.125f;
        float dy = (a20 - a00 + 2.f * (a21 - a01) + a22 - a02) * 0.125f;
        int gy = TY0 - 12 + py, gx = TX0 - 12 + px;
        bool in = ((unsigned)gy < H) && ((unsigned)gx < W);
        float rv = in ? reb[gy * W + gx] : 0.f;
        s_t[0][py][px] = in ? -rv * dx : 0.f;
        s_t[1][py][px] = in ? -rv * dy : 0.f;
        if (py >= 12 && py < 44 && px >= 12 && px < 44) {
            grads_l[(size_t)(b * 2 + 0) * HW + gy * W + gx] = dx;
            grads_l[(size_t)(b * 2 + 1) * HW + gy * W + gx] = dy;
        }
    }
    __syncthreads();

    float g[KSIZE]; gaussw(g);

    // vertical blur: 2ch x 32 rows x 56 cols
    for (int q = tid; q < 2 * 32 * 56; q += 256) {
        int ch = q / (32 * 56), r = q % (32 * 56);
        int vy = r / 56, vx = r % 56;
        float acc = 0.f;
#pragma unroll
        for (int k = 0; k < KSIZE; ++k) acc = fmaf(g[k], s_t[ch][vy + k][vx], acc);
        s_vb[ch][vy][vx] = acc;
    }
    __syncthreads();

    // horizontal blur: 2ch x 32 x 32 -> field (B,H,W,2)
    for (int q = tid; q < 2 * 32 * 32; q += 256) {
        int ch = q / 1024, p = q % 1024;
        int hy = p / 32, hx = p % 32;
        float acc = 0.f;
#pragma unroll
        for (int k = 0; k < KSIZE; ++k) acc = fmaf(g[k], s_vb[ch][hy][hx + k], acc);
        field_l[((size_t)(b * H + TY0 + hy) * W + TX0 + hx) * 2 + ch] = acc;
    }
}

// ------------------------------------------------- fused res_block v2
// tile 32x16 output, 256 threads, weights via wave-uniform global reads
// (compiler scalarizes to s_load -> SGPR operand in v_fma; no LDS weights).

#define NCH 10   // channels per chunk (10 chunks)

__global__ __launch_bounds__(256)
void resblock_kernel(const float* __restrict__ res_i, const float* __restrict__ img,
                     const float* __restrict__ w1, const float* __restrict__ b1,
                     const float* __restrict__ w2, float* __restrict__ res_out) {
    __shared__ float s_in[2][20][37];      // input tile + halo2 (18+2 rows, 36 cols)
    __shared__ float s_hid[NCH][18][35];   // hidden (34x18 positions, 1-halo)

    const int tid = threadIdx.x;
    const int b = blockIdx.z;
    const int TY0 = blockIdx.y * 16, TX0 = blockIdx.x * 32;

    // stage inputs: rows TY0-2..TY0+17 (20), cols TX0-2..TX0+33 (36), zero-pad
    for (int q = tid; q < 20 * 36; q += 256) {
        int ry = q / 36, rx = q % 36;
        int gy = TY0 - 2 + ry, gx = TX0 - 2 + rx;
        bool v = ((unsigned)gy < H) && ((unsigned)gx < W);
        size_t gp = (size_t)b * HW + gy * W + gx;
        s_in[0][ry][rx] = v ? res_i[gp] : 0.f;
        s_in[1][ry][rx] = v ? img[gp]   : 0.f;
    }
    __syncthreads();

    const int y2 = tid >> 4;            // 0..15 output row
    const int x2 = (tid & 15) * 2;      // 0..30 output col pair
    float acc0 = 0.f, acc1 = 0.f;

    for (int cc = 0; cc < HID / NCH; ++cc) {
        // conv1: 306 horizontal position-pairs over hidden 18x34
        for (int q = tid; q < 17 * 18; q += 256) {
            int hy = q / 17, hx2 = (q % 17) * 2;
            int gy = TY0 - 1 + hy, gx0 = TX0 - 1 + hx2;
            float xv[2][3][4];
#pragma unroll
            for (int ic = 0; ic < 2; ++ic)
#pragma unroll
                for (int j = 0; j < 3; ++j)
#pragma unroll
                    for (int i = 0; i < 4; ++i)
                        xv[ic][j][i] = s_in[ic][hy + j][hx2 + i];
            bool gyok = ((unsigned)gy < H);
            bool in0 = gyok && ((unsigned)gx0 < W);
            bool in1 = gyok && ((unsigned)(gx0 + 1) < W);
#pragma unroll 2
            for (int c = 0; c < NCH; ++c) {
                int ch = cc * NCH + c;
                const float* wp = w1 + ch * 18;       // uniform -> s_load
                float bv = b1[ch];
                float h0 = bv, h1 = bv;
#pragma unroll
                for (int ic = 0; ic < 2; ++ic)
#pragma unroll
                    for (int j = 0; j < 3; ++j)
#pragma unroll
                        for (int i = 0; i < 3; ++i) {
                            float wv = wp[ic * 9 + j * 3 + i];
                            h0 = fmaf(wv, xv[ic][j][i],     h0);
                            h1 = fmaf(wv, xv[ic][j][i + 1], h1);
                        }
                h0 = (h0 >= 0.f) ? h0 : SLOPE * h0;
                h1 = (h1 >= 0.f) ? h1 : SLOPE * h1;
                s_hid[c][hy][hx2]     = in0 ? h0 : 0.f;
                s_hid[c][hy][hx2 + 1] = in1 ? h1 : 0.f;
            }
        }
        __syncthreads();

        // conv2: each thread 2 adjacent pixels, weights via SGPR
        for (int c = 0; c < NCH; ++c) {
            const float* wq = w2 + (cc * NCH + c) * 9;   // uniform -> s_load
#pragma unroll
            for (int j = 0; j < 3; ++j) {
                float v0 = s_hid[c][y2 + j][x2 + 0];
                float v1 = s_hid[c][y2 + j][x2 + 1];
                float v2 = s_hid[c][y2 + j][x2 + 2];
                float v3 = s_hid[c][y2 + j][x2 + 3];
                float w0 = wq[j * 3 + 0], w1v = wq[j * 3 + 1], w2v = wq[j * 3 + 2];
                acc0 = fmaf(w0, v0, acc0); acc0 = fmaf(w1v, v1, acc0); acc0 = fmaf(w2v, v2, acc0);
                acc1 = fmaf(w0, v1, acc1); acc1 = fmaf(w1v, v2, acc1); acc1 = fmaf(w2v, v3, acc1);
            }
        }
        __syncthreads();
    }

    size_t gp = (size_t)b * HW + (TY0 + y2) * W + TX0 + x2;
    res_out[gp]     = res_i[gp]     + acc0 * (1.f / (float)L);
    res_out[gp + 1] = res_i[gp + 1] + acc1 * (1.f / (float)L);
}

// ------------------------------------------------- E+F+G fused warp/update

__global__ void efg_kernel(const float* __restrict__ field,
                           const float* __restrict__ res_new,
                           const float* __restrict__ rd_old, float* __restrict__ rd_new,
                           int nc_old,
                           const float* __restrict__ phi_old, float* __restrict__ phi_new,
                           const float* __restrict__ seg, const float* __restrict__ source,
                           float* __restrict__ image_buf, float* __restrict__ image_out) {
    int idx = blockIdx.x * 256 + threadIdx.x;
    if (idx >= B * HW) return;
    int b = idx / HW, p = idx % HW;
    int y = p / W, x = p % W;

    float fx = field[((size_t)(b * HW + p)) * 2 + 0];
    float fy = field[((size_t)(b * HW + p)) * 2 + 1];
    float sx = (float)x - fx * (1.f / (float)L);
    float sy = (float)y - fy * (1.f / (float)L);

    float xf = floorf(sx), yf = floorf(sy);
    int x0 = (int)xf, y0 = (int)yf;
    float wx = sx - xf, wy = sy - yf;
    float mx0 = (x0 >= 0 && x0 < W) ? 1.f : 0.f;
    float mx1 = (x0 + 1 >= 0 && x0 + 1 < W) ? 1.f : 0.f;
    float my0 = (y0 >= 0 && y0 < H) ? 1.f : 0.f;
    float my1 = (y0 + 1 >= 0 && y0 + 1 < H) ? 1.f : 0.f;
    float W00 = (1.f - wx) * (1.f - wy) * mx0 * my0;
    float W01 = wx * (1.f - wy) * mx1 * my0;
    float W10 = (1.f - wx) * wy * mx0 * my1;
    float W11 = wx * wy * mx1 * my1;
    int xc0 = min(max(x0, 0), W - 1), xc1 = min(max(x0 + 1, 0), W - 1);
    int yc0 = min(max(y0, 0), H - 1), yc1 = min(max(y0 + 1, 0), H - 1);
    int o00 = yc0 * W + xc0, o01 = yc0 * W + xc1;
    int o10 = yc1 * W + xc0, o11 = yc1 * W + xc1;

    float s = 0.f;
    for (int c = 0; c < nc_old; ++c) {
        const float* im = rd_old + (size_t)(b * 11 + c) * HW;
        float v = W00 * im[o00] + W01 * im[o01] + W10 * im[o10] + W11 * im[o11];
        rd_new[(size_t)(b * 11 + c) * HW + p] = v;
        if (c > 0) s += v;
    }
    float rn = res_new[idx];
    rd_new[(size_t)(b * 11 + nc_old) * HW + p] = rn;
    s += rn;

    const float* phx = phi_old + (size_t)(b * 2 + 0) * HW;
    const float* phy = phi_old + (size_t)(b * 2 + 1) * HW;
    float pxn = W00 * phx[o00] + W01 * phx[o01] + W10 * phx[o10] + W11 * phx[o11];
    float pyn = W00 * phy[o00] + W01 * phy[o01] + W10 * phy[o10] + W11 * phy[o11];
    phi_new[(size_t)(b * 2 + 0) * HW + p] = pxn;
    phi_new[(size_t)(b * 2 + 1) * HW + p] = pyn;

    float mask = bilin(seg + (size_t)b * HW, pxn, pyn);
    float sw   = bilin(source + (size_t)b * HW, pxn, pyn);
    float img = sw + s * (MU * MU / (float)L) * mask;
    image_buf[idx] = img;
    image_out[idx] = img;
}

// ---------------------------------------------------------------- launch

extern "C" void kernel_launch(void* const* d_in, const int* in_sizes, int n_in,
                              void* d_out, int out_size, void* d_ws, size_t ws_size,
                              hipStream_t stream) {
    const float* source = (const float*)d_in[0];
    const float* seg    = (const float*)d_in[1];
    const float* z0     = (const float*)d_in[2];
    const float* w1     = (const float*)d_in[3];
    const float* b1     = (const float*)d_in[4];
    const float* w2     = (const float*)d_in[5];
    float* out = (float*)d_out;

    const size_t nPix = (size_t)B * HW;
    float* out_image  = out;
    float* out_fields = out + nPix;
    float* out_res    = out_fields + (size_t)L * nPix * 2;
    float* out_grads  = out_res + (size_t)(L + 1) * nPix;

    float* ws        = (float*)d_ws;
    float* image_buf = ws;                       // B*HW
    float* phi_buf0  = image_buf + nPix;         // 2*B*HW
    float* phi_buf1  = phi_buf0 + 2 * nPix;      // 2*B*HW
    float* rd_buf0   = phi_buf1 + 2 * nPix;      // 11*B*HW
    float* rd_buf1   = rd_buf0 + 11 * nPix;      // 11*B*HW
    float* phi_buf[2] = { phi_buf0, phi_buf1 };
    float* rd_buf[2]  = { rd_buf0, rd_buf1 };

    dim3 blk(256);
    int gPix = (int)((nPix + 255) / 256);

    init_kernel<<<gPix, blk, 0, stream>>>(source, z0, out_res, rd_buf[0], phi_buf[0], image_buf);

    int cur = 0;
    for (int i = 0; i < L; ++i) {
        dim3 gF(W / 32, H / 32, B);
        field_kernel<<<gF, 256, 0, stream>>>(image_buf, out_res + (size_t)i * nPix,
                                             out_grads + (size_t)i * 2 * nPix,
                                             out_fields + (size_t)i * 2 * nPix);
        dim3 gD(W / 32, H / 16, B);
        resblock_kernel<<<gD, 256, 0, stream>>>(out_res + (size_t)i * nPix, image_buf,
                                                w1 + (size_t)i * HID * 18,
                                                b1 + (size_t)i * HID,
                                                w2 + (size_t)i * HID * 9,
                                                out_res + (size_t)(i + 1) * nPix);
        efg_kernel<<<gPix, blk, 0, stream>>>(out_fields + (size_t)i * 2 * nPix,
                                             out_res + (size_t)(i + 1) * nPix,
                                             rd_buf[cur], rd_buf[cur ^ 1], i + 1,
                                             phi_buf[cur], phi_buf[cur ^ 1],
                                             seg, source, image_buf, out_image);
        cur ^= 1;
    }
}